// Round 1
// baseline (160.181 us; speedup 1.0000x reference)
//
#include <hip/hip_runtime.h>
#include <hip/hip_bf16.h>
#include <math.h>

#define NNODES 131072
#define BN 32

typedef __attribute__((ext_vector_type(8))) short bf16x8;
typedef __attribute__((ext_vector_type(4))) float f32x4;

__device__ __forceinline__ short f2b(float f) {
  union { float f; unsigned u; } x; x.f = f;
  unsigned r = x.u + 0x7fffu + ((x.u >> 16) & 1u);
  return (short)(r >> 16);
}
__device__ __forceinline__ float b2f(short s) {
  union { unsigned u; float f; } x; x.u = ((unsigned)(unsigned short)s) << 16;
  return x.f;
}
__device__ __forceinline__ bf16x8 cvt8(const float* __restrict__ p) {
  float4 qa = *(const float4*)p;
  float4 qb = *(const float4*)(p + 4);
  bf16x8 fr;
  fr[0] = f2b(qa.x); fr[1] = f2b(qa.y); fr[2] = f2b(qa.z); fr[3] = f2b(qa.w);
  fr[4] = f2b(qb.x); fr[5] = f2b(qb.y); fr[6] = f2b(qb.z); fr[7] = f2b(qb.w);
  return fr;
}

// LDS arenas (bytes):
//   Vt   [96][64] bf16  stride 128, swz   @ 0      (12288)  -- union GATE [32][64] f32 (8192)
//   SC   [32][256] bf16 stride 512, swz   @ 12288  (16384)
//   VH   [96][128] bf16 stride 256, swz   @ 28672  (24576)  -- union VST [32][192] f32 (24576)
//   SOUT [32][128] bf16 stride 256, swz   @ 53248  (8192)
// total 61440 <= 64KB

__global__ __launch_bounds__(256, 2)
void gvp_kernel(const float* __restrict__ s_in, const float* __restrict__ V_in,
                const float* __restrict__ W_h, const float* __restrict__ W_V,
                const float* __restrict__ W_s_w, const float* __restrict__ W_s_b,
                const float* __restrict__ W_g_w, const float* __restrict__ W_g_b,
                float* __restrict__ s_out_g, float* __restrict__ V_out_g)
{
  __shared__ char smem[61440];
  char*  const Vt   = smem;
  float* const GATE = (float*)smem;
  char*  const SC   = smem + 12288;
  char*  const VH   = smem + 28672;
  float* const VST  = (float*)(smem + 28672);
  char*  const SOUT = smem + 53248;

  const int t    = threadIdx.x;
  const int lane = t & 63;
  const int w    = t >> 6;
  const int l15  = lane & 15;
  const int lk8  = (lane >> 4) << 3;  // 0,8,16,24 : k-offset of A/B frag
  const int r4   = (lane >> 4) << 2;  // 0,4,8,12  : row-offset of C frag
  const long n0  = (long)blockIdx.x * BN;

  // ---- stage V tile: [32 nodes][64 v][3 c] f32 -> Vt[(c*32+nl)][v] bf16 swz ----
  {
    const float4* Vb = (const float4*)(V_in + n0 * 192);
    #pragma unroll
    for (int i = 0; i < 6; ++i) {
      int idx = t + 256 * i;
      float4 q = Vb[idx];
      int f = idx << 2;
      #pragma unroll
      for (int e = 0; e < 4; ++e) {
        int ff = f + e;
        int nl = ff / 192;
        int r  = ff - nl * 192;
        int v  = r / 3;
        int c  = r - v * 3;
        int row = (c << 5) + nl;
        unsigned a = (unsigned)(row * 128) + (((unsigned)(v * 2)) ^ (unsigned)((row & 7) << 4));
        *(short*)(Vt + a) = f2b(((const float*)&q)[e]);
      }
    }
  }
  // ---- stage s tile -> SC[:, 0:128] bf16 swz ----
  {
    const float4* sb = (const float4*)(s_in + n0 * 128);
    #pragma unroll
    for (int i = 0; i < 4; ++i) {
      int idx = t + 256 * i;
      float4 q = sb[idx];
      int f = idx << 2;
      int nl = f >> 7;
      int k  = f & 127;
      ushort4 p;
      p.x = (unsigned short)f2b(q.x);
      p.y = (unsigned short)f2b(q.y);
      p.z = (unsigned short)f2b(q.z);
      p.w = (unsigned short)f2b(q.w);
      unsigned a = (unsigned)(nl * 512) + (((unsigned)(k * 2)) ^ (unsigned)((nl & 7) << 4));
      *(ushort4*)(SC + a) = p;
    }
  }
  __syncthreads();

  // ---- GEMM1: Vh[(c,nl)][h] = sum_v Vt * W_h[h][v];  96x128, K=64 ----
  f32x4 acc1[6][2];
  #pragma unroll
  for (int rt = 0; rt < 6; ++rt) {
    f32x4 z = {0.f, 0.f, 0.f, 0.f};
    acc1[rt][0] = z; acc1[rt][1] = z;
  }
  {
    bf16x8 bf1[2][2];
    #pragma unroll
    for (int cc = 0; cc < 2; ++cc) {
      int h = ((2 * w + cc) << 4) + l15;
      #pragma unroll
      for (int ks = 0; ks < 2; ++ks)
        bf1[cc][ks] = cvt8(W_h + h * 64 + (ks << 5) + lk8);
    }
    #pragma unroll
    for (int rt = 0; rt < 6; ++rt) {
      int row = (rt << 4) + l15;
      unsigned sw = (unsigned)((row & 7) << 4);
      bf16x8 af0 = *(const bf16x8*)(Vt + row * 128 + (((unsigned)(lk8 * 2)) ^ sw));
      bf16x8 af1 = *(const bf16x8*)(Vt + row * 128 + (((unsigned)((32 + lk8) * 2)) ^ sw));
      #pragma unroll
      for (int cc = 0; cc < 2; ++cc) {
        acc1[rt][cc] = __builtin_amdgcn_mfma_f32_16x16x32_bf16(af0, bf1[cc][0], acc1[rt][cc], 0, 0, 0);
        acc1[rt][cc] = __builtin_amdgcn_mfma_f32_16x16x32_bf16(af1, bf1[cc][1], acc1[rt][cc], 0, 0, 0);
      }
    }
  }
  // ---- write Vh bf16 to LDS + Vh_norm (f32 accums, rows r/r+32/r+64 live in same lane) ----
  #pragma unroll
  for (int cc = 0; cc < 2; ++cc) {
    int col = ((2 * w + cc) << 4) + l15;
    #pragma unroll
    for (int rt = 0; rt < 6; ++rt) {
      #pragma unroll
      for (int i = 0; i < 4; ++i) {
        int row = (rt << 4) + r4 + i;
        unsigned a = (unsigned)(row * 256) + (((unsigned)(col * 2)) ^ (unsigned)((row & 7) << 4));
        *(short*)(VH + a) = f2b(acc1[rt][cc][i]);
      }
    }
    #pragma unroll
    for (int rt = 0; rt < 2; ++rt) {
      #pragma unroll
      for (int i = 0; i < 4; ++i) {
        int nl = (rt << 4) + r4 + i;
        float x0 = acc1[rt][cc][i];
        float x1 = acc1[rt + 2][cc][i];
        float x2 = acc1[rt + 4][cc][i];
        float nrm = sqrtf(x0 * x0 + x1 * x1 + x2 * x2);
        int k = 128 + col;
        unsigned a = (unsigned)(nl * 512) + (((unsigned)(k * 2)) ^ (unsigned)((nl & 7) << 4));
        *(short*)(SC + a) = f2b(nrm);
      }
    }
  }
  __syncthreads();

  // ---- GEMM2: V_out_pre[(c,nl)][o] = sum_h VH * W_V[o][h];  96x64, K=128 ----
  f32x4 acc2[6];
  #pragma unroll
  for (int rt = 0; rt < 6; ++rt) { f32x4 z = {0.f,0.f,0.f,0.f}; acc2[rt] = z; }
  {
    bf16x8 bf2[4];
    int o = (w << 4) + l15;
    #pragma unroll
    for (int ks = 0; ks < 4; ++ks)
      bf2[ks] = cvt8(W_V + o * 128 + (ks << 5) + lk8);
    #pragma unroll
    for (int rt = 0; rt < 6; ++rt) {
      int row = (rt << 4) + l15;
      unsigned sw = (unsigned)((row & 7) << 4);
      #pragma unroll
      for (int ks = 0; ks < 4; ++ks) {
        bf16x8 a = *(const bf16x8*)(VH + row * 256 + (((unsigned)((((ks << 5) + lk8)) * 2)) ^ sw));
        acc2[rt] = __builtin_amdgcn_mfma_f32_16x16x32_bf16(a, bf2[ks], acc2[rt], 0, 0, 0);
      }
    }
  }

  // ---- GEMM3: s_out[nl][so] = relu(sum_k SC * W_s_w[so][k] + b);  32x128, K=256 ----
  f32x4 acc3[2][2];
  {
    f32x4 z = {0.f,0.f,0.f,0.f};
    acc3[0][0] = z; acc3[0][1] = z; acc3[1][0] = z; acc3[1][1] = z;
  }
  #pragma unroll
  for (int ks = 0; ks < 8; ++ks) {
    bf16x8 b3[2];
    #pragma unroll
    for (int cc = 0; cc < 2; ++cc) {
      int o = ((w + 4 * cc) << 4) + l15;
      b3[cc] = cvt8(W_s_w + o * 256 + (ks << 5) + lk8);
    }
    #pragma unroll
    for (int rt = 0; rt < 2; ++rt) {
      int row = (rt << 4) + l15;
      bf16x8 a = *(const bf16x8*)(SC + row * 512 +
                   (((unsigned)(((ks << 5) + lk8) * 2)) ^ ((unsigned)((row & 7) << 4))));
      acc3[rt][0] = __builtin_amdgcn_mfma_f32_16x16x32_bf16(a, b3[0], acc3[rt][0], 0, 0, 0);
      acc3[rt][1] = __builtin_amdgcn_mfma_f32_16x16x32_bf16(a, b3[1], acc3[rt][1], 0, 0, 0);
    }
  }
  #pragma unroll
  for (int cc = 0; cc < 2; ++cc) {
    int col = ((w + 4 * cc) << 4) + l15;
    float bias = W_s_b[col];
    #pragma unroll
    for (int rt = 0; rt < 2; ++rt) {
      #pragma unroll
      for (int i = 0; i < 4; ++i) {
        int row = (rt << 4) + r4 + i;
        float val = fmaxf(acc3[rt][cc][i] + bias, 0.0f);
        s_out_g[(n0 + row) * 128 + col] = val;
        unsigned a = (unsigned)(row * 256) + (((unsigned)(col * 2)) ^ (unsigned)((row & 7) << 4));
        *(short*)(SOUT + a) = f2b(val);
      }
    }
  }
  __syncthreads();

  // ---- GEMM4: gate[nl][o] = sigmoid(sum_k SOUT * W_g_w[o][k] + b);  32x64, K=128 ----
  f32x4 acc4[2];
  { f32x4 z = {0.f,0.f,0.f,0.f}; acc4[0] = z; acc4[1] = z; }
  {
    int o = (w << 4) + l15;
    #pragma unroll
    for (int ks = 0; ks < 4; ++ks) {
      bf16x8 b4 = cvt8(W_g_w + o * 128 + (ks << 5) + lk8);
      #pragma unroll
      for (int rt = 0; rt < 2; ++rt) {
        int row = (rt << 4) + l15;
        bf16x8 a = *(const bf16x8*)(SOUT + row * 256 +
                     (((unsigned)(((ks << 5) + lk8) * 2)) ^ ((unsigned)((row & 7) << 4))));
        acc4[rt] = __builtin_amdgcn_mfma_f32_16x16x32_bf16(a, b4, acc4[rt], 0, 0, 0);
      }
    }
    float bias = W_g_b[o];
    #pragma unroll
    for (int rt = 0; rt < 2; ++rt) {
      #pragma unroll
      for (int i = 0; i < 4; ++i) {
        int nl = (rt << 4) + r4 + i;
        float x = acc4[rt][i] + bias;
        GATE[nl * 64 + o] = 1.0f / (1.0f + __expf(-x));
      }
    }
  }
  __syncthreads();

  // ---- gate apply: VST[nl][o*3+c] = acc2 * gate ----
  {
    int col = (w << 4) + l15;
    #pragma unroll
    for (int rt = 0; rt < 6; ++rt) {
      #pragma unroll
      for (int i = 0; i < 4; ++i) {
        int row = (rt << 4) + r4 + i;
        int c  = row >> 5;
        int nl = row & 31;
        VST[nl * 192 + col * 3 + c] = acc2[rt][i] * GATE[nl * 64 + col];
      }
    }
  }
  __syncthreads();

  // ---- coalesced V_out store ----
  {
    float4* Vo = (float4*)(V_out_g + n0 * 192);
    const float4* Vs = (const float4*)VST;
    #pragma unroll
    for (int i = 0; i < 6; ++i) {
      int idx = t + 256 * i;
      Vo[idx] = Vs[idx];
    }
  }
}

extern "C" void kernel_launch(void* const* d_in, const int* in_sizes, int n_in,
                              void* d_out, int out_size, void* d_ws, size_t ws_size,
                              hipStream_t stream) {
  const float* s_in  = (const float*)d_in[0];
  const float* V_in  = (const float*)d_in[1];
  const float* W_h   = (const float*)d_in[2];
  const float* W_V   = (const float*)d_in[3];
  const float* W_s_w = (const float*)d_in[4];
  const float* W_s_b = (const float*)d_in[5];
  const float* W_g_w = (const float*)d_in[6];
  const float* W_g_b = (const float*)d_in[7];
  float* out = (float*)d_out;
  float* s_out_g = out;
  float* V_out_g = out + (size_t)NNODES * 128;
  hipLaunchKernelGGL(gvp_kernel, dim3(NNODES / BN), dim3(256), 0, stream,
                     s_in, V_in, W_h, W_V, W_s_w, W_s_b, W_g_w, W_g_b,
                     s_out_g, V_out_g);
}

// Round 2
// 117.584 us; speedup vs baseline: 1.3623x; 1.3623x over previous
//
#include <hip/hip_runtime.h>
#include <hip/hip_bf16.h>
#include <math.h>

#define NNODES 131072
#define BN 32

typedef __attribute__((ext_vector_type(8))) short bf16x8;
typedef __attribute__((ext_vector_type(4))) float f32x4;

// bf16 weights, converted once per launch by prep_kernel:
//   W_h [128*64] @0 | W_V [64*128] @8192 | W_s [128*256] @16384 | W_g [64*128] @49152
__device__ short g_w[57344];

__device__ __forceinline__ short f2b(float f) {
  union { float f; unsigned u; } x; x.f = f;
  unsigned r = x.u + 0x7fffu + ((x.u >> 16) & 1u);
  return (short)(r >> 16);
}

__global__ void prep_kernel(const float* __restrict__ W_h, const float* __restrict__ W_V,
                            const float* __restrict__ W_s_w, const float* __restrict__ W_g_w) {
  int i4 = (blockIdx.x * 256 + threadIdx.x) * 4;
  if (i4 >= 57344) return;
  const float* src;
  if (i4 < 8192)       src = W_h   + i4;
  else if (i4 < 16384) src = W_V   + (i4 - 8192);
  else if (i4 < 49152) src = W_s_w + (i4 - 16384);
  else                 src = W_g_w + (i4 - 49152);
  float4 q = *(const float4*)src;
  short4 p;
  p.x = f2b(q.x); p.y = f2b(q.y); p.z = f2b(q.z); p.w = f2b(q.w);
  *(short4*)(g_w + i4) = p;
}

// LDS arenas (49152 B total -> 3 blocks/CU):
//   region A @0     (24576): Vt [96][64]bf16 s128 swz  ->(B2)-> VH [96][128]bf16 s256 swz ->(B5)-> VST [32][192] f32
//   region B @24576 (16384): SC [32][256]bf16 s512 swz ->(B4)-> GATE [32][64] f32
//   region C @40960 (8192) : SOUT [32][128]bf16 s256 swz

__global__ __launch_bounds__(256, 3)
void gvp_kernel(const float* __restrict__ s_in, const float* __restrict__ V_in,
                const float* __restrict__ W_s_b, const float* __restrict__ W_g_b,
                float* __restrict__ s_out_g, float* __restrict__ V_out_g)
{
  __shared__ __align__(16) char smem[49152];
  char*  const Vt   = smem;
  char*  const VH   = smem;
  float* const VST  = (float*)smem;
  char*  const SC   = smem + 24576;
  float* const GATE = (float*)(smem + 24576);
  char*  const SOUT = smem + 40960;

  const short* const g_wh = g_w;
  const short* const g_wv = g_w + 8192;
  const short* const g_ws = g_w + 16384;
  const short* const g_wg = g_w + 49152;

  const int t    = threadIdx.x;
  const int lane = t & 63;
  const int w    = t >> 6;
  const int l15  = lane & 15;
  const int lk8  = (lane >> 4) << 3;  // 0,8,16,24 : k-offset of A/B frag
  const int r4   = (lane >> 4) << 2;  // 0,4,8,12  : row-offset of C frag
  const long n0  = (long)blockIdx.x * BN;

  // ---- stage V tile: [32 nodes][64 v][3 c] f32 -> Vt[(c*32+nl)][v] bf16 swz ----
  {
    const float4* Vb = (const float4*)(V_in + n0 * 192);
    #pragma unroll
    for (int i = 0; i < 6; ++i) {
      int idx = t + 256 * i;
      float4 q = Vb[idx];
      int f = idx << 2;
      #pragma unroll
      for (int e = 0; e < 4; ++e) {
        int ff = f + e;
        int nl = ff / 192;
        int r  = ff - nl * 192;
        int v  = r / 3;
        int c  = r - v * 3;
        int row = (c << 5) + nl;
        unsigned a = (unsigned)(row * 128) + (((unsigned)(v * 2)) ^ (unsigned)((row & 7) << 4));
        *(short*)(Vt + a) = f2b(((const float*)&q)[e]);
      }
    }
  }
  // ---- stage s tile -> SC[:, 0:128] bf16 swz ----
  {
    const float4* sb = (const float4*)(s_in + n0 * 128);
    #pragma unroll
    for (int i = 0; i < 4; ++i) {
      int idx = t + 256 * i;
      float4 q = sb[idx];
      int f = idx << 2;
      int nl = f >> 7;
      int k  = f & 127;
      ushort4 p;
      p.x = (unsigned short)f2b(q.x);
      p.y = (unsigned short)f2b(q.y);
      p.z = (unsigned short)f2b(q.z);
      p.w = (unsigned short)f2b(q.w);
      unsigned a = (unsigned)(nl * 512) + (((unsigned)(k * 2)) ^ (unsigned)((nl & 7) << 4));
      *(ushort4*)(SC + a) = p;
    }
  }
  __syncthreads();  // B1

  // ---- GEMM1: Vh[(c,nl)][h] = sum_v Vt * W_h[h][v];  96x128, K=64 ----
  f32x4 acc1[6][2];
  #pragma unroll
  for (int rt = 0; rt < 6; ++rt) {
    f32x4 z = {0.f, 0.f, 0.f, 0.f};
    acc1[rt][0] = z; acc1[rt][1] = z;
  }
  {
    bf16x8 bf1[2][2];
    #pragma unroll
    for (int cc = 0; cc < 2; ++cc) {
      int h = ((2 * w + cc) << 4) + l15;
      #pragma unroll
      for (int ks = 0; ks < 2; ++ks)
        bf1[cc][ks] = *(const bf16x8*)(g_wh + h * 64 + (ks << 5) + lk8);
    }
    #pragma unroll
    for (int rt = 0; rt < 6; ++rt) {
      int row = (rt << 4) + l15;
      unsigned sw = (unsigned)((row & 7) << 4);
      bf16x8 af0 = *(const bf16x8*)(Vt + row * 128 + (((unsigned)(lk8 * 2)) ^ sw));
      bf16x8 af1 = *(const bf16x8*)(Vt + row * 128 + (((unsigned)((32 + lk8) * 2)) ^ sw));
      #pragma unroll
      for (int cc = 0; cc < 2; ++cc) {
        acc1[rt][cc] = __builtin_amdgcn_mfma_f32_16x16x32_bf16(af0, bf1[cc][0], acc1[rt][cc], 0, 0, 0);
        acc1[rt][cc] = __builtin_amdgcn_mfma_f32_16x16x32_bf16(af1, bf1[cc][1], acc1[rt][cc], 0, 0, 0);
      }
    }
  }
  __syncthreads();  // B2: all Vt reads done, VH may overlay

  // ---- write Vh bf16 to LDS (overlay Vt) + Vh_norm -> SC[:,128:] ----
  #pragma unroll
  for (int cc = 0; cc < 2; ++cc) {
    int col = ((2 * w + cc) << 4) + l15;
    #pragma unroll
    for (int rt = 0; rt < 6; ++rt) {
      #pragma unroll
      for (int i = 0; i < 4; ++i) {
        int row = (rt << 4) + r4 + i;
        unsigned a = (unsigned)(row * 256) + (((unsigned)(col * 2)) ^ (unsigned)((row & 7) << 4));
        *(short*)(VH + a) = f2b(acc1[rt][cc][i]);
      }
    }
    #pragma unroll
    for (int rt = 0; rt < 2; ++rt) {
      #pragma unroll
      for (int i = 0; i < 4; ++i) {
        int nl = (rt << 4) + r4 + i;
        float x0 = acc1[rt][cc][i];
        float x1 = acc1[rt + 2][cc][i];
        float x2 = acc1[rt + 4][cc][i];
        float nrm = sqrtf(x0 * x0 + x1 * x1 + x2 * x2);
        int k = 128 + col;
        unsigned a = (unsigned)(nl * 512) + (((unsigned)(k * 2)) ^ (unsigned)((nl & 7) << 4));
        *(short*)(SC + a) = f2b(nrm);
      }
    }
  }
  __syncthreads();  // B3

  // ---- GEMM2: V_out_pre[(c,nl)][o] = sum_h VH * W_V[o][h];  96x64, K=128 ----
  f32x4 acc2[6];
  #pragma unroll
  for (int rt = 0; rt < 6; ++rt) { f32x4 z = {0.f,0.f,0.f,0.f}; acc2[rt] = z; }
  {
    bf16x8 bf2[4];
    int o = (w << 4) + l15;
    #pragma unroll
    for (int ks = 0; ks < 4; ++ks)
      bf2[ks] = *(const bf16x8*)(g_wv + o * 128 + (ks << 5) + lk8);
    #pragma unroll
    for (int rt = 0; rt < 6; ++rt) {
      int row = (rt << 4) + l15;
      unsigned sw = (unsigned)((row & 7) << 4);
      #pragma unroll
      for (int ks = 0; ks < 4; ++ks) {
        bf16x8 a = *(const bf16x8*)(VH + row * 256 + (((unsigned)((((ks << 5) + lk8)) * 2)) ^ sw));
        acc2[rt] = __builtin_amdgcn_mfma_f32_16x16x32_bf16(a, bf2[ks], acc2[rt], 0, 0, 0);
      }
    }
  }

  // ---- GEMM3: s_out[nl][so] = relu(sum_k SC * W_s_w[so][k] + b);  32x128, K=256 ----
  f32x4 acc3[2][2];
  {
    f32x4 z = {0.f,0.f,0.f,0.f};
    acc3[0][0] = z; acc3[0][1] = z; acc3[1][0] = z; acc3[1][1] = z;
  }
  #pragma unroll
  for (int ks = 0; ks < 8; ++ks) {
    bf16x8 b3[2];
    #pragma unroll
    for (int cc = 0; cc < 2; ++cc) {
      int o = ((w + 4 * cc) << 4) + l15;
      b3[cc] = *(const bf16x8*)(g_ws + o * 256 + (ks << 5) + lk8);
    }
    #pragma unroll
    for (int rt = 0; rt < 2; ++rt) {
      int row = (rt << 4) + l15;
      bf16x8 a = *(const bf16x8*)(SC + row * 512 +
                   (((unsigned)(((ks << 5) + lk8) * 2)) ^ ((unsigned)((row & 7) << 4))));
      acc3[rt][0] = __builtin_amdgcn_mfma_f32_16x16x32_bf16(a, b3[0], acc3[rt][0], 0, 0, 0);
      acc3[rt][1] = __builtin_amdgcn_mfma_f32_16x16x32_bf16(a, b3[1], acc3[rt][1], 0, 0, 0);
    }
  }
  #pragma unroll
  for (int cc = 0; cc < 2; ++cc) {
    int col = ((w + 4 * cc) << 4) + l15;
    float bias = W_s_b[col];
    #pragma unroll
    for (int rt = 0; rt < 2; ++rt) {
      #pragma unroll
      for (int i = 0; i < 4; ++i) {
        int row = (rt << 4) + r4 + i;
        float val = fmaxf(acc3[rt][cc][i] + bias, 0.0f);
        s_out_g[(n0 + row) * 128 + col] = val;
        unsigned a = (unsigned)(row * 256) + (((unsigned)(col * 2)) ^ (unsigned)((row & 7) << 4));
        *(short*)(SOUT + a) = f2b(val);
      }
    }
  }
  __syncthreads();  // B4: SC reads + VH reads done

  // ---- GEMM4: gate[nl][o] = sigmoid(sum_k SOUT * W_g_w[o][k] + b);  32x64, K=128 ----
  f32x4 acc4[2];
  { f32x4 z = {0.f,0.f,0.f,0.f}; acc4[0] = z; acc4[1] = z; }
  {
    int o = (w << 4) + l15;
    #pragma unroll
    for (int ks = 0; ks < 4; ++ks) {
      bf16x8 b4 = *(const bf16x8*)(g_wg + o * 128 + (ks << 5) + lk8);
      #pragma unroll
      for (int rt = 0; rt < 2; ++rt) {
        int row = (rt << 4) + l15;
        bf16x8 a = *(const bf16x8*)(SOUT + row * 256 +
                     (((unsigned)(((ks << 5) + lk8) * 2)) ^ ((unsigned)((row & 7) << 4))));
        acc4[rt] = __builtin_amdgcn_mfma_f32_16x16x32_bf16(a, b4, acc4[rt], 0, 0, 0);
      }
    }
    float bias = W_g_b[o];
    #pragma unroll
    for (int rt = 0; rt < 2; ++rt) {
      #pragma unroll
      for (int i = 0; i < 4; ++i) {
        int nl = (rt << 4) + r4 + i;
        float x = acc4[rt][i] + bias;
        GATE[nl * 64 + o] = 1.0f / (1.0f + __expf(-x));
      }
    }
  }
  __syncthreads();  // B5

  // ---- gate apply: VST[nl][o*3+c] = acc2 * gate (overlay region A) ----
  {
    int col = (w << 4) + l15;
    #pragma unroll
    for (int rt = 0; rt < 6; ++rt) {
      #pragma unroll
      for (int i = 0; i < 4; ++i) {
        int row = (rt << 4) + r4 + i;
        int c  = row >> 5;
        int nl = row & 31;
        VST[nl * 192 + col * 3 + c] = acc2[rt][i] * GATE[nl * 64 + col];
      }
    }
  }
  __syncthreads();  // B6

  // ---- coalesced V_out store ----
  {
    float4* Vo = (float4*)(V_out_g + n0 * 192);
    const float4* Vs = (const float4*)VST;
    #pragma unroll
    for (int i = 0; i < 6; ++i) {
      int idx = t + 256 * i;
      Vo[idx] = Vs[idx];
    }
  }
}

extern "C" void kernel_launch(void* const* d_in, const int* in_sizes, int n_in,
                              void* d_out, int out_size, void* d_ws, size_t ws_size,
                              hipStream_t stream) {
  const float* s_in  = (const float*)d_in[0];
  const float* V_in  = (const float*)d_in[1];
  const float* W_h   = (const float*)d_in[2];
  const float* W_V   = (const float*)d_in[3];
  const float* W_s_w = (const float*)d_in[4];
  const float* W_s_b = (const float*)d_in[5];
  const float* W_g_w = (const float*)d_in[6];
  const float* W_g_b = (const float*)d_in[7];
  float* out = (float*)d_out;
  float* s_out_g = out;
  float* V_out_g = out + (size_t)NNODES * 128;
  hipLaunchKernelGGL(prep_kernel, dim3(57344 / (256 * 4)), dim3(256), 0, stream,
                     W_h, W_V, W_s_w, W_g_w);
  hipLaunchKernelGGL(gvp_kernel, dim3(NNODES / BN), dim3(256), 0, stream,
                     s_in, V_in, W_s_b, W_g_b, s_out_g, V_out_g);
}